// Round 6
// baseline (95.670 us; speedup 1.0000x reference)
//
#include <hip/hip_runtime.h>

// CIN layer fused, round 6.
//
// out[b,n,w] = bias[n] + sum_{r,j} x0[b, w&31, 2r+h] * xk[b, j, 2r+h] * W[n,r,j],  h=w>>5
//   phase B: G[n,h,r] = sum_j W[n,r,j] * xk[b,j,2r+h]
//            W register-resident (thread (n,wv) owns rows 2wv,2wv+1; 64 VGPR,
//            loaded once per block). xk read DIRECTLY FROM GLOBAL via a
//            wave-uniform float4 (readfirstlane index -> 1 L2 line per instr /
//            s_load) -- no xk LDS at all (R5 analysis: the 2048 broadcast
//            ds_read_b128 were ~4-5 us of LDS pipe).
//   phase C: out = bias + x0T^T * G. 8n x 8w register tiles (64 acc), 4 waves
//            wv in {0,5,10,15} (one per SIMD under either wave->SIMD mapping),
//            2048 FMA/wave uncontended; LDS instrs halved vs 4x4 tiling.
//            G LDS layout r*136 + h*68 + n spreads reads over all 32 banks.
//
// Grid 256 x 1024 threads, 4 batches/block, 105 KB LDS (1 block/CU), 2 barriers.

constexpr int ST0 = 36;    // x0T row stride (words)
constexpr int GR  = 136;   // G words per r (h=0 at +0, h=1 at +68)
constexpr int GB  = 32 * GR;  // 4352 words per batch

__global__ __launch_bounds__(1024)
__attribute__((amdgpu_waves_per_eu(4, 4)))
void cin_fused(const float* __restrict__ x0,
               const float* __restrict__ xk,
               const float* __restrict__ W,
               const float* __restrict__ bias,
               float* __restrict__ out)
{
    __shared__ __align__(16) float x0T[4 * 64 * ST0];  // 36 KB [kb][fi][t^swz]
    __shared__ __align__(16) float Gs[4 * GB];         // 68 KB [kb][r][h][n]

    const int tid  = threadIdx.x;
    const int b0   = blockIdx.x * 4;
    const int lane = tid & 63;
    const int wv   = tid >> 6;
    const int r0   = 2 * wv;

    // ---- issue x0 staging loads FIRST (so their vmcnt clears before W's)
    const float4* x0src = reinterpret_cast<const float4*>(x0 + (size_t)b0 * 2048);
    const float4 a0 = x0src[tid];          // batches 0/1
    const float4 a1 = x0src[tid + 1024];   // batches 2/3

    // ---- W rows r0, r0+1 of filter `lane` -> 64 VGPRs (once per block)
    float w0reg[32], w1reg[32];
    {
        const float4* wp = reinterpret_cast<const float4*>(W + ((size_t)lane * 32 + r0) * 32);
        #pragma unroll
        for (int q = 0; q < 8; ++q) {
            const float4 v = wp[q];
            w0reg[4*q+0] = v.x; w0reg[4*q+1] = v.y; w0reg[4*q+2] = v.z; w0reg[4*q+3] = v.w;
        }
        #pragma unroll
        for (int q = 0; q < 8; ++q) {
            const float4 v = wp[8 + q];
            w1reg[4*q+0] = v.x; w1reg[4*q+1] = v.y; w1reg[4*q+2] = v.z; w1reg[4*q+3] = v.w;
        }
    }

    // ---- commit x0T (transpose + XOR swizzle; <=2-way writes)
    {
        const int kb  = tid >> 9;               // 0/1 (a0), +2 (a1)
        const int u   = tid & 511;
        const int st  = u >> 4;                 // source row t
        const int sf4 = u & 15;                 // fi0 = 4*sf4
        const int sts = st ^ (4 * (sf4 & 7));   // swizzled t
        float* rA = &x0T[(kb    ) * 64 * ST0 + (4 * sf4) * ST0];
        float* rB = &x0T[(kb + 2) * 64 * ST0 + (4 * sf4) * ST0];
        rA[0 * ST0 + sts] = a0.x; rA[1 * ST0 + sts] = a0.y;
        rA[2 * ST0 + sts] = a0.z; rA[3 * ST0 + sts] = a0.w;
        rB[0 * ST0 + sts] = a1.x; rB[1 * ST0 + sts] = a1.y;
        rB[2 * ST0 + sts] = a1.z; rB[3 * ST0 + sts] = a1.w;
    }
    __syncthreads();

    // ---- phase B: G for rows r0,r0+1, both h, 4 batches; xk wave-uniform from global
    const int su = __builtin_amdgcn_readfirstlane(wv);
    for (int kb = 0; kb < 4; ++kb) {
        const float4* pk4 = reinterpret_cast<const float4*>(xk + (size_t)(b0 + kb) * 2048);
        float a00 = 0.f, a01 = 0.f, a10 = 0.f, a11 = 0.f;
        #pragma unroll
        for (int q = 0; q < 4; ++q) {        // groups of 8 j: <=8 float4 in flight
            float4 kv[8];
            #pragma unroll
            for (int m = 0; m < 8; ++m)
                kv[m] = pk4[(q * 8 + m) * 16 + su];   // xk[j][4wv..4wv+3], uniform addr
            #pragma unroll
            for (int m = 0; m < 8; ++m) {
                const int j = q * 8 + m;
                a00 = fmaf(w0reg[j], kv[m].x, a00);   // (r0,   h=0)
                a01 = fmaf(w0reg[j], kv[m].y, a01);   // (r0,   h=1)
                a10 = fmaf(w1reg[j], kv[m].z, a10);   // (r0+1, h=0)
                a11 = fmaf(w1reg[j], kv[m].w, a11);   // (r0+1, h=1)
            }
        }
        float* gb = &Gs[kb * GB];
        gb[(r0    ) * GR +      lane] = a00;   // banks lane%32: 2-way, free
        gb[(r0    ) * GR + 68 + lane] = a01;
        gb[(r0 + 1) * GR +      lane] = a10;
        gb[(r0 + 1) * GR + 68 + lane] = a11;
    }
    __syncthreads();

    // ---- phase C: waves {0,5,10,15} (one per SIMD either mapping), 8n x 8w tiles
    if (wv % 5 == 0) {
        const int ckb = wv / 5;                // batch 0..3
        const int l   = lane;
        const int n0  = (l >> 3) * 8;          // 0,8,...,56
        const int w0c = (l & 7) * 8;           // 0,8,...,56 (within one h)
        const int h   = w0c >> 5;
        const int t0  = w0c & 31;

        const float4 bva = *reinterpret_cast<const float4*>(bias + n0);
        const float4 bvb = *reinterpret_cast<const float4*>(bias + n0 + 4);

        float acc[8][8];
        #pragma unroll
        for (int i = 0; i < 8; ++i) {
            acc[0][i] = bva.x; acc[1][i] = bva.y; acc[2][i] = bva.z; acc[3][i] = bva.w;
            acc[4][i] = bvb.x; acc[5][i] = bvb.y; acc[6][i] = bvb.z; acc[7][i] = bvb.w;
        }

        const float* xbase = &x0T[ckb * 64 * ST0];
        const float* gbase = &Gs[ckb * GB + h * 68];

        #pragma unroll 4
        for (int r = 0; r < 32; ++r) {
            const int fi = 2 * r + h;
            const int p  = 4 * ((fi >> 2) & 7);          // staging swizzle
            const float4 xa = *reinterpret_cast<const float4*>(&xbase[fi * ST0 + (t0 ^ p)]);
            const float4 xb = *reinterpret_cast<const float4*>(&xbase[fi * ST0 + ((t0 + 4) ^ p)]);
            const float4 g0 = *reinterpret_cast<const float4*>(&gbase[r * GR + n0]);
            const float4 g1 = *reinterpret_cast<const float4*>(&gbase[r * GR + n0 + 4]);
            const float ge[8] = {g0.x, g0.y, g0.z, g0.w, g1.x, g1.y, g1.z, g1.w};
            const float xv[8] = {xa.x, xa.y, xa.z, xa.w, xb.x, xb.y, xb.z, xb.w};
            #pragma unroll
            for (int e = 0; e < 8; ++e)
                #pragma unroll
                for (int i = 0; i < 8; ++i)
                    acc[e][i] = fmaf(ge[e], xv[i], acc[e][i]);
        }

        float* ob = out + (size_t)(b0 + ckb) * 4096;
        #pragma unroll
        for (int e = 0; e < 8; ++e) {
            *reinterpret_cast<float4*>(&ob[(n0 + e) * 64 + w0c]) =
                make_float4(acc[e][0], acc[e][1], acc[e][2], acc[e][3]);
            *reinterpret_cast<float4*>(&ob[(n0 + e) * 64 + w0c + 4]) =
                make_float4(acc[e][4], acc[e][5], acc[e][6], acc[e][7]);
        }
    }
}

extern "C" void kernel_launch(void* const* d_in, const int* in_sizes, int n_in,
                              void* d_out, int out_size, void* d_ws, size_t ws_size,
                              hipStream_t stream) {
    const float* x0   = (const float*)d_in[0];
    const float* xk   = (const float*)d_in[1];
    const float* W    = (const float*)d_in[2];
    const float* bias = (const float*)d_in[3];
    float* out = (float*)d_out;

    cin_fused<<<dim3(256), dim3(1024), 0, stream>>>(x0, xk, W, bias, out);
}

// Round 11
// 87.105 us; speedup vs baseline: 1.0983x; 1.0983x over previous
//
#include <hip/hip_runtime.h>

// CIN layer fused, round 10 resubmit (GPU-acquisition timeout; kernel never ran).
// = R9 with the w_reorder stride bug fixed: W4 is float4*, per-filter stride is
// 256 float4, not 32 (R9 loaded wrong W slices, absmax 13.4).
//
// out[b,n,w] = bias[n] + sum_{r,j} x0[b,w&31,2r+h] * xk[b,j,2r+h] * W[n,r,j],  h=w>>5
//   phase B: G[n,fi] = sum_j W[n,fi>>1,j]*xk[j,fi].  W register-resident
//            (thread (n=lane, wv) owns rows 2wv,2wv+1, coalesced via reordered
//            Wt in d_ws). xk read from GLOBAL at wave-uniform addresses
//            (1 L2 line/instr, zero LDS traffic). Output packed f16x2 to LDS.
//   phase C: out = bias + sum_rp dot2(Gp[n][rp], xP[t][rp]) -- f16x2 pairs over
//            consecutive r, v_dot2_f32_f16, ALL 16 waves, 4n x 4w tiles,
//            2 ds_read_b128 per rp per thread. All LDS patterns <=2-way (free).
//
// Grid 256 x 1024 threads, 4 batches/block, 50 KB LDS, 1 barrier.

typedef __fp16 hh2 __attribute__((ext_vector_type(2)));   // matches cvt_pkrtz/fdot2

constexpr int XPS = 36;   // xP t-stride in hh2 units (16B-aligned, bank-spread)

// Pre-kernel: Wt[(wv*16+q)*64 + lane] = W4[lane*256 + (2wv + (q>>3))*8 + (q&7)]
// so the main kernel's W-load (thread (wv,lane), q=0..15) is fully coalesced.
__global__ __launch_bounds__(256)
void w_reorder(const float4* __restrict__ W4, float4* __restrict__ Wt)
{
    const int o    = blockIdx.x * 256 + threadIdx.x;   // 0..16383
    const int lane = o & 63;
    const int q    = (o >> 6) & 15;
    const int wv   = o >> 10;
    Wt[o] = W4[lane * 256 + (2 * wv + (q >> 3)) * 8 + (q & 7)];
}

__global__ __launch_bounds__(1024)
__attribute__((amdgpu_waves_per_eu(4, 4)))
void cin_fused(const float* __restrict__ x0,
               const float* __restrict__ xk,
               const float4* __restrict__ Wt,
               const float* __restrict__ bias,
               float* __restrict__ out)
{
    // xP[kb][h][rp][t] = (x0[t][4rp+h], x0[t][4rp+2+h])  f16x2   (18.4 KB)
    // Gp[kb][h][rp][n] = (G[n][2rp][h], G[n][2rp+1][h])  f16x2   (32 KB)
    __shared__ __align__(16) hh2 xP[4][2][16][XPS];
    __shared__ __align__(16) hh2 Gp[4][2][16][64];

    const int tid  = threadIdx.x;
    const int b0   = blockIdx.x * 4;
    const int lane = tid & 63;
    const int wv   = tid >> 6;

    // ---- issue x0 staging loads (coalesced)
    const float4* x0src = reinterpret_cast<const float4*>(x0 + (size_t)b0 * 2048);
    const float4 a0 = x0src[tid];          // batches b0, b0+1
    const float4 a1 = x0src[tid + 1024];   // batches b0+2, b0+3

    // ---- W rows 2wv, 2wv+1 of filter `lane` -> 64 VGPRs, COALESCED via Wt
    float w0reg[32], w1reg[32];
    {
        const float4* wp = Wt + (size_t)wv * 1024 + lane;
        #pragma unroll
        for (int q = 0; q < 8; ++q) {
            const float4 v = wp[q * 64];           // 64 lanes x 16B contiguous
            w0reg[4*q+0] = v.x; w0reg[4*q+1] = v.y; w0reg[4*q+2] = v.z; w0reg[4*q+3] = v.w;
        }
        #pragma unroll
        for (int q = 0; q < 8; ++q) {
            const float4 v = wp[(q + 8) * 64];
            w1reg[4*q+0] = v.x; w1reg[4*q+1] = v.y; w1reg[4*q+2] = v.z; w1reg[4*q+3] = v.w;
        }
    }

    // ---- commit xP (pack fi-pairs (4f+h, 4f+2+h) from the float4; banks (4f+t): 2-way)
    {
        const int kb = tid >> 9;        // 0/1 for a0; +2 for a1
        const int u  = tid & 511;
        const int t  = u >> 4;
        const int f  = u & 15;
        xP[kb    ][0][f][t] = __builtin_amdgcn_cvt_pkrtz(a0.x, a0.z);
        xP[kb    ][1][f][t] = __builtin_amdgcn_cvt_pkrtz(a0.y, a0.w);
        xP[kb + 2][0][f][t] = __builtin_amdgcn_cvt_pkrtz(a1.x, a1.z);
        xP[kb + 2][1][f][t] = __builtin_amdgcn_cvt_pkrtz(a1.y, a1.w);
    }

    // ---- phase B: wave-uniform global xk loads; 128 fmac per kb per thread
    const int su = __builtin_amdgcn_readfirstlane(wv);
    for (int kb = 0; kb < 4; ++kb) {
        const float4* pk4 = reinterpret_cast<const float4*>(xk + (size_t)(b0 + kb) * 2048) + su;
        float a00 = 0.f, a01 = 0.f, a10 = 0.f, a11 = 0.f;
        #pragma unroll
        for (int q = 0; q < 4; ++q) {             // groups of 8 j: 8 loads in flight
            float4 kv[8];
            #pragma unroll
            for (int m = 0; m < 8; ++m)
                kv[m] = pk4[(q * 8 + m) * 16];    // xk[j][4wv..4wv+3], uniform addr
            #pragma unroll
            for (int m = 0; m < 8; ++m) {
                const int j = q * 8 + m;
                a00 = fmaf(w0reg[j], kv[m].x, a00);   // (r=2wv,   h=0)
                a01 = fmaf(w0reg[j], kv[m].y, a01);   // (r=2wv,   h=1)
                a10 = fmaf(w1reg[j], kv[m].z, a10);   // (r=2wv+1, h=0)
                a11 = fmaf(w1reg[j], kv[m].w, a11);   // (r=2wv+1, h=1)
            }
        }
        // Gp[kb][h][rp=wv][n=lane]: banks lane%32 -> 2-way, free
        Gp[kb][0][wv][lane] = __builtin_amdgcn_cvt_pkrtz(a00, a10);
        Gp[kb][1][wv][lane] = __builtin_amdgcn_cvt_pkrtz(a01, a11);
    }
    __syncthreads();

    // ---- phase C: ALL 16 waves; thread = (kb, 4n x 4w tile); dot2 over r-pairs
    {
        const int kb  = tid >> 8;          // wave-uniform (256-aligned groups)
        const int t2  = tid & 255;
        const int n0  = (t2 >> 4) * 4;
        const int w0c = (t2 & 15) * 4;
        const int h   = w0c >> 5;
        const int t0  = w0c & 31;

        const float4 bv = *reinterpret_cast<const float4*>(bias + n0);
        float acc[4][4];
        #pragma unroll
        for (int i = 0; i < 4; ++i) {
            acc[0][i] = bv.x; acc[1][i] = bv.y; acc[2][i] = bv.z; acc[3][i] = bv.w;
        }

        #pragma unroll
        for (int rp = 0; rp < 16; ++rp) {
            union { float4 f; hh2 p[4]; } xu, guv;
            // banks: xv (4rp+t0)%32, gv n0%32, h-halves alias 2-way -> free
            xu.f  = *reinterpret_cast<const float4*>(&xP[kb][h][rp][t0]);
            guv.f = *reinterpret_cast<const float4*>(&Gp[kb][h][rp][n0]);
            #pragma unroll
            for (int e = 0; e < 4; ++e) {
                #pragma unroll
                for (int i = 0; i < 4; ++i) {
#if __has_builtin(__builtin_amdgcn_fdot2)
                    acc[e][i] = __builtin_amdgcn_fdot2(guv.p[e], xu.p[i], acc[e][i], false);
#else
                    acc[e][i] += (float)guv.p[e].x * (float)xu.p[i].x
                               + (float)guv.p[e].y * (float)xu.p[i].y;
#endif
                }
            }
        }

        float* ob = out + (size_t)(b0 + kb) * 4096;
        #pragma unroll
        for (int e = 0; e < 4; ++e) {
            *reinterpret_cast<float4*>(&ob[(n0 + e) * 64 + w0c]) =
                make_float4(acc[e][0], acc[e][1], acc[e][2], acc[e][3]);
        }
    }
}

extern "C" void kernel_launch(void* const* d_in, const int* in_sizes, int n_in,
                              void* d_out, int out_size, void* d_ws, size_t ws_size,
                              hipStream_t stream) {
    const float* x0   = (const float*)d_in[0];
    const float* xk   = (const float*)d_in[1];
    const float* W    = (const float*)d_in[2];
    const float* bias = (const float*)d_in[3];
    float* out = (float*)d_out;
    float4* Wt = (float4*)d_ws;   // 256 KB scratch, rewritten every call

    w_reorder<<<dim3(64), dim3(256), 0, stream>>>((const float4*)W, Wt);
    cin_fused<<<dim3(256), dim3(1024), 0, stream>>>(x0, xk, Wt, bias, out);
}